// Round 3
// baseline (2405.823 us; speedup 1.0000x reference)
//
#include <hip/hip_runtime.h>
#include <hip/hip_bf16.h>

#define T_STEPS 512
#define BATCH   1024
#define HD1     80
#define HD2     100

#define W1_DW   (HD1 / 2)              // 40 packed dwords per lstm1 row
#define W2_DW   ((HD1 + HD2) / 2)      // 90 packed dwords per lstm2 row
#define NR1     (4 * HD1)              // 320 rows
#define NR2     (4 * HD2)              // 400 rows

typedef _Float16 half2_t __attribute__((ext_vector_type(2)));

union HU { unsigned int u; half2_t h; };
static __device__ __forceinline__ half2_t bch(unsigned int u) { HU x; x.u = u; return x.h; }
static __device__ __forceinline__ unsigned int bcu(half2_t h) { HU x; x.h = h; return x.u; }

static __device__ __forceinline__ float dot2(half2_t a, half2_t b, float c) {
    return __builtin_amdgcn_fdot2(a, b, c, false);
}

static __device__ __forceinline__ unsigned int packh(float a, float b) {
    half2_t p; p.x = (_Float16)a; p.y = (_Float16)b; return bcu(p);
}

// ---------------------------------------------------------------------------
// Prep: pack weights to f16 dwords, transposed [dword][row] for coalescing.
// ---------------------------------------------------------------------------
__global__ __launch_bounds__(256)
void prep_kernel(const float* __restrict__ W_hh1,
                 const float* __restrict__ W_ih2,
                 const float* __restrict__ W_hh2,
                 unsigned int* __restrict__ w1t,
                 unsigned int* __restrict__ w2t)
{
    int i = blockIdx.x * 256 + threadIdx.x;
    if (i < W1_DW * NR1) {
        int d = i / NR1, j = i % NR1;
        w1t[i] = packh(W_hh1[j * HD1 + 2 * d], W_hh1[j * HD1 + 2 * d + 1]);
    } else if (i < W1_DW * NR1 + W2_DW * NR2) {
        int k = i - W1_DW * NR1;
        int d = k / NR2, j = k % NR2;
        unsigned int p;
        if (d < W1_DW)
            p = packh(W_ih2[j * HD1 + 2 * d], W_ih2[j * HD1 + 2 * d + 1]);
        else {
            int dd = d - W1_DW;
            p = packh(W_hh2[j * HD2 + 2 * dd], W_hh2[j * HD2 + 2 * dd + 1]);
        }
        w2t[k] = p;
    }
}

// ---------------------------------------------------------------------------
// Phase 1: LSTM layer 1, ONE batch per block (1024 blocks x 320 threads).
// Thread j owns gate-row j; 40 weight dwords in VGPRs (unconditional loads).
// h state: uint4[10] in LDS (8 f16 per entry). 2 indep acc chains.
// Writes relu(h1) f16 to ws, layout [t][b][k].
// ---------------------------------------------------------------------------
__global__ __launch_bounds__(NR1, 4)
void lstm1_kernel(const float* __restrict__ x,
                  const float* __restrict__ W_ih1,
                  const unsigned int* __restrict__ w1t,
                  const float* __restrict__ b_ih1,
                  const float* __restrict__ b_hh1,
                  _Float16* __restrict__ h1relu)
{
    const int j = threadIdx.x;
    const int b = blockIdx.x;
    const int q = j / HD1;
    const int m = j % HD1;

    unsigned int w[W1_DW];
#pragma unroll
    for (int d = 0; d < W1_DW; d++) w[d] = w1t[d * NR1 + j];
    const float wih  = W_ih1[j];
    const float bias = b_ih1[j] + b_hh1[j];

    __shared__ uint4 hp[HD1 / 8];     // 10 entries, 8 f16 values each
    __shared__ float gates[NR1];
    __shared__ float xs[T_STEPS];

    if (j < HD1 / 8) hp[j] = make_uint4(0u, 0u, 0u, 0u);
    for (int idx = j; idx < T_STEPS; idx += NR1)
        xs[idx] = x[(size_t)b * T_STEPS + idx];
    float c = 0.f;
    __syncthreads();

    for (int t = 0; t < T_STEPS; t++) {
        float accP = fmaf(wih, xs[t], bias);
        float accQ = 0.f;
#pragma unroll
        for (int k4 = 0; k4 < HD1 / 8; k4++) {
            uint4 U = hp[k4];
            accP = dot2(bch(w[4 * k4 + 0]), bch(U.x), accP);
            accQ = dot2(bch(w[4 * k4 + 1]), bch(U.y), accQ);
            accP = dot2(bch(w[4 * k4 + 2]), bch(U.z), accP);
            accQ = dot2(bch(w[4 * k4 + 3]), bch(U.w), accQ);
        }
        float z = accP + accQ;
        z = (q == 2) ? 2.f * z : z;
        float s = 1.f / (1.f + __expf(-z));
        gates[j] = (q == 2) ? (2.f * s - 1.f) : s;
        __syncthreads();                      // gates ready

        if (j < HD1) {
            float gi = gates[m];
            float gf = gates[HD1 + m];
            float gg = gates[2 * HD1 + m];
            float go = gates[3 * HD1 + m];
            c = fmaf(gf, c, gi * gg);
            float th = 2.f / (1.f + __expf(-2.f * c)) - 1.f;
            float h = go * th;
            float hn = __shfl_down(h, 1, 64);
            if ((m & 1) == 0) {
                ((unsigned int*)hp)[m >> 1] = packh(h, hn);
                *(unsigned int*)(h1relu + ((size_t)t * BATCH + b) * HD1 + m) =
                    packh(fmaxf(h, 0.f), fmaxf(hn, 0.f));
            }
        }
        __syncthreads();                      // hp(t+1) ready
    }
}

// ---------------------------------------------------------------------------
// Phase 2: LSTM layer 2. 1024 blocks x 512 threads, ONE batch per block.
//
// R3 CHANGE: launch-bounds semantics discovery. Observed across R0-R2:
//   (512,4) -> VGPR_Count 64;  (512,2) -> VGPR_Count 128.
// i.e. for this toolchain the 2nd arg acts as min BLOCKS/CU (CUDA-style):
// cap = 512 / (arg * 8waves / 4simd). R2's (512,4) silently requested a
// 64-reg budget -> w[90] reloaded from L2 every step (22MB spill writes,
// VALUBusy 60%). Fix: keep NB=1 (pressure ~110) and declare (512,2) ->
// 128-reg cap >= pressure -> zero spill AND 2 resident blocks/CU.
// Rows 0..399 own gate-rows; threads 400..439 stage h1 with 1-step prefetch.
// Dot loops run on ALL threads (uniform); 4 indep acc chains. 2 barriers/step.
// ---------------------------------------------------------------------------
__global__ __launch_bounds__(512, 2)
void lstm2_kernel(const _Float16* __restrict__ h1relu,
                  const unsigned int* __restrict__ w2t,
                  const float* __restrict__ b_ih2,
                  const float* __restrict__ b_hh2,
                  float* __restrict__ h2last)
{
    const int j  = threadIdx.x;
    const int b0 = blockIdx.x;                  // one batch per block
    const int jr = (j < NR2) ? j : (NR2 - 1);   // clamp: loads unconditional
    const bool rowActive = (j < NR2);
    const int q = jr / HD2;
    const int m = jr % HD2;

    unsigned int w[W2_DW];
#pragma unroll
    for (int d = 0; d < W2_DW; d++) w[d] = w2t[d * NR2 + jr];
    const float bias = b_ih2[jr] + b_hh2[jr];

    __shared__ uint4 h1p[HD1 / 8];    // 10 uint4 = 40 dwords = 80 f16 (h1 of this batch)
    __shared__ uint4 h2p[13];         // 50 dwords used; entry 12 .z/.w = zero pad
    __shared__ float gates[NR2];

    if (j < 13) h2p[j] = make_uint4(0u, 0u, 0u, 0u);
    float c0 = 0.f;

    // stagers: threads 400..439 each own one h1 dword
    const int  sj = j - NR2;
    const bool stager = (sj >= 0) && (sj < W1_DW);
    const int  sk = ((sj >= 0) && (sj < W1_DW)) ? sj : 0;
    unsigned int pf = 0;
    if (stager)
        pf = *(const unsigned int*)(h1relu + (size_t)b0 * HD1 + 2 * sk);

    for (int t = 0; t < T_STEPS; t++) {
        if (stager)
            ((unsigned int*)h1p)[sk] = pf;     // stage h1(t)
        __syncthreads();                       // h1p(t) + h2p(t) ready

        if (stager && t + 1 < T_STEPS)
            pf = *(const unsigned int*)(h1relu +
                     ((size_t)(t + 1) * BATCH + b0) * HD1 + 2 * sk);

        // dots on ALL threads (uniform control flow; garbage for j>=400)
        float aP = bias, aQ = 0.f, aR = 0.f, aS = 0.f;
#pragma unroll
        for (int k4 = 0; k4 < HD1 / 8; k4++) {         // 10 iters, 40 dot2
            uint4 U = h1p[k4];
            aP = dot2(bch(w[4 * k4 + 0]), bch(U.x), aP);
            aQ = dot2(bch(w[4 * k4 + 1]), bch(U.y), aQ);
            aR = dot2(bch(w[4 * k4 + 2]), bch(U.z), aR);
            aS = dot2(bch(w[4 * k4 + 3]), bch(U.w), aS);
        }
#pragma unroll
        for (int k4 = 0; k4 < 12; k4++) {              // 12 iters, 48 dot2
            uint4 U = h2p[k4];
            aP = dot2(bch(w[W1_DW + 4 * k4 + 0]), bch(U.x), aP);
            aQ = dot2(bch(w[W1_DW + 4 * k4 + 1]), bch(U.y), aQ);
            aR = dot2(bch(w[W1_DW + 4 * k4 + 2]), bch(U.z), aR);
            aS = dot2(bch(w[W1_DW + 4 * k4 + 3]), bch(U.w), aS);
        }
        {   // trailing h2 dims 96..99 (dwords 48,49)
            uint4 U = h2p[12];
            aP = dot2(bch(w[W1_DW + 48]), bch(U.x), aP);
            aQ = dot2(bch(w[W1_DW + 49]), bch(U.y), aQ);
        }
        float z = (aP + aR) + (aQ + aS);
        z = (q == 2) ? 2.f * z : z;
        float s = 1.f / (1.f + __expf(-z));
        if (rowActive)
            gates[j] = (q == 2) ? (2.f * s - 1.f) : s;
        __syncthreads();                       // gates ready

        if (j < HD2) {
            float gi = gates[m];
            float gf = gates[HD2 + m];
            float gg = gates[2 * HD2 + m];
            float go = gates[3 * HD2 + m];
            c0 = fmaf(gf, c0, gi * gg);
            float th = 2.f / (1.f + __expf(-2.f * c0)) - 1.f;
            float h0 = go * th;
            float h0n = __shfl_down(h0, 1, 64);
            if ((m & 1) == 0)
                ((unsigned int*)h2p)[m >> 1] = packh(h0, h0n);
            if (t == T_STEPS - 1)
                h2last[(size_t)b0 * HD2 + m] = fmaxf(h0, 0.f);
        }
        // next loop-top stage + barrier covers h2p visibility
    }
}

// ---------------------------------------------------------------------------
// Head: out[b] = W_l2 @ relu(W_l1 @ h2last[b] + b_l1) + b_l2
// ---------------------------------------------------------------------------
__global__ __launch_bounds__(64)
void head_kernel(const float* __restrict__ h2last,
                 const float* __restrict__ W_l1,
                 const float* __restrict__ b_l1,
                 const float* __restrict__ W_l2,
                 const float* __restrict__ b_l2,
                 float* __restrict__ out)
{
    int b = blockIdx.x * 64 + threadIdx.x;
    if (b >= BATCH) return;
    const float* h = h2last + (size_t)b * HD2;
    float o = b_l2[0];
#pragma unroll
    for (int u = 0; u < 10; u++) {
        float s = b_l1[u];
#pragma unroll
        for (int k = 0; k < HD2; k++) s = fmaf(W_l1[u * HD2 + k], h[k], s);
        o = fmaf(W_l2[u], fmaxf(s, 0.f), o);
    }
    out[b] = o;
}

extern "C" void kernel_launch(void* const* d_in, const int* in_sizes, int n_in,
                              void* d_out, int out_size, void* d_ws, size_t ws_size,
                              hipStream_t stream)
{
    const float* x     = (const float*)d_in[0];
    const float* W_ih1 = (const float*)d_in[1];
    const float* W_hh1 = (const float*)d_in[2];
    const float* b_ih1 = (const float*)d_in[3];
    const float* b_hh1 = (const float*)d_in[4];
    const float* W_ih2 = (const float*)d_in[5];
    const float* W_hh2 = (const float*)d_in[6];
    const float* b_ih2 = (const float*)d_in[7];
    const float* b_hh2 = (const float*)d_in[8];
    const float* W_l1  = (const float*)d_in[9];
    const float* b_l1  = (const float*)d_in[10];
    const float* W_l2  = (const float*)d_in[11];
    const float* b_l2  = (const float*)d_in[12];
    float* out = (float*)d_out;

    // ws layout: h1relu f16 [t][b][k] (84 MB) | h2last f32 | w1t | w2t
    char* p = (char*)d_ws;
    _Float16* h1relu = (_Float16*)p;           p += (size_t)T_STEPS * BATCH * HD1 * 2;
    float* h2last    = (float*)p;              p += (size_t)BATCH * HD2 * 4;
    unsigned int* w1t = (unsigned int*)p;      p += (size_t)W1_DW * NR1 * 4;
    unsigned int* w2t = (unsigned int*)p;

    int prep_n = W1_DW * NR1 + W2_DW * NR2;
    hipLaunchKernelGGL(prep_kernel, dim3((prep_n + 255) / 256), dim3(256), 0, stream,
                       W_hh1, W_ih2, W_hh2, w1t, w2t);
    hipLaunchKernelGGL(lstm1_kernel, dim3(BATCH), dim3(NR1), 0, stream,
                       x, W_ih1, w1t, b_ih1, b_hh1, h1relu);
    hipLaunchKernelGGL(lstm2_kernel, dim3(BATCH), dim3(512), 0, stream,
                       h1relu, w2t, b_ih2, b_hh2, h2last);
    hipLaunchKernelGGL(head_kernel, dim3(BATCH / 64), dim3(64), 0, stream,
                       h2last, W_l1, b_l1, W_l2, b_l2, out);
}

// Round 4
// 2327.148 us; speedup vs baseline: 1.0338x; 1.0338x over previous
//
#include <hip/hip_runtime.h>
#include <hip/hip_bf16.h>

#define T_STEPS 512
#define BATCH   1024
#define HD1     80
#define HD2     100

#define W1_DW   (HD1 / 2)              // 40 packed dwords per lstm1 row
#define W2_DW   ((HD1 + HD2) / 2)      // 90 packed dwords per lstm2 row
#define NR1     (4 * HD1)              // 320 rows
#define NR2     (4 * HD2)              // 400 rows

#define HALF_DW 45                     // split-K: 45 weight dwords per worker
#define HP_PAD  48                     // hp dword stride per half (16B-aligned)

typedef _Float16 half2_t __attribute__((ext_vector_type(2)));

union HU { unsigned int u; half2_t h; };
static __device__ __forceinline__ half2_t bch(unsigned int u) { HU x; x.u = u; return x.h; }
static __device__ __forceinline__ unsigned int bcu(half2_t h) { HU x; x.h = h; return x.u; }

static __device__ __forceinline__ float dot2(half2_t a, half2_t b, float c) {
    return __builtin_amdgcn_fdot2(a, b, c, false);
}

static __device__ __forceinline__ unsigned int packh(float a, float b) {
    half2_t p; p.x = (_Float16)a; p.y = (_Float16)b; return bcu(p);
}

// ---------------------------------------------------------------------------
// Prep: pack weights to f16 dwords, transposed [dword][row] for coalescing.
// (unchanged: dword k of a row = k<40 ? W_ih2 dword k : W_hh2 dword k-40)
// ---------------------------------------------------------------------------
__global__ __launch_bounds__(256)
void prep_kernel(const float* __restrict__ W_hh1,
                 const float* __restrict__ W_ih2,
                 const float* __restrict__ W_hh2,
                 unsigned int* __restrict__ w1t,
                 unsigned int* __restrict__ w2t)
{
    int i = blockIdx.x * 256 + threadIdx.x;
    if (i < W1_DW * NR1) {
        int d = i / NR1, j = i % NR1;
        w1t[i] = packh(W_hh1[j * HD1 + 2 * d], W_hh1[j * HD1 + 2 * d + 1]);
    } else if (i < W1_DW * NR1 + W2_DW * NR2) {
        int k = i - W1_DW * NR1;
        int d = k / NR2, j = k % NR2;
        unsigned int p;
        if (d < W1_DW)
            p = packh(W_ih2[j * HD1 + 2 * d], W_ih2[j * HD1 + 2 * d + 1]);
        else {
            int dd = d - W1_DW;
            p = packh(W_hh2[j * HD2 + 2 * dd], W_hh2[j * HD2 + 2 * dd + 1]);
        }
        w2t[k] = p;
    }
}

// ---------------------------------------------------------------------------
// Phase 1: LSTM layer 1 (unchanged this round).
// ---------------------------------------------------------------------------
__global__ __launch_bounds__(NR1, 4)
void lstm1_kernel(const float* __restrict__ x,
                  const float* __restrict__ W_ih1,
                  const unsigned int* __restrict__ w1t,
                  const float* __restrict__ b_ih1,
                  const float* __restrict__ b_hh1,
                  _Float16* __restrict__ h1relu)
{
    const int j = threadIdx.x;
    const int b = blockIdx.x;
    const int q = j / HD1;
    const int m = j % HD1;

    unsigned int w[W1_DW];
#pragma unroll
    for (int d = 0; d < W1_DW; d++) w[d] = w1t[d * NR1 + j];
    const float wih  = W_ih1[j];
    const float bias = b_ih1[j] + b_hh1[j];

    __shared__ uint4 hp[HD1 / 8];     // 10 entries, 8 f16 values each
    __shared__ float gates[NR1];
    __shared__ float xs[T_STEPS];

    if (j < HD1 / 8) hp[j] = make_uint4(0u, 0u, 0u, 0u);
    for (int idx = j; idx < T_STEPS; idx += NR1)
        xs[idx] = x[(size_t)b * T_STEPS + idx];
    float c = 0.f;
    __syncthreads();

    for (int t = 0; t < T_STEPS; t++) {
        float accP = fmaf(wih, xs[t], bias);
        float accQ = 0.f;
#pragma unroll
        for (int k4 = 0; k4 < HD1 / 8; k4++) {
            uint4 U = hp[k4];
            accP = dot2(bch(w[4 * k4 + 0]), bch(U.x), accP);
            accQ = dot2(bch(w[4 * k4 + 1]), bch(U.y), accQ);
            accP = dot2(bch(w[4 * k4 + 2]), bch(U.z), accP);
            accQ = dot2(bch(w[4 * k4 + 3]), bch(U.w), accQ);
        }
        float z = accP + accQ;
        z = (q == 2) ? 2.f * z : z;
        float s = 1.f / (1.f + __expf(-z));
        gates[j] = (q == 2) ? (2.f * s - 1.f) : s;
        __syncthreads();                      // gates ready

        if (j < HD1) {
            float gi = gates[m];
            float gf = gates[HD1 + m];
            float gg = gates[2 * HD1 + m];
            float go = gates[3 * HD1 + m];
            c = fmaf(gf, c, gi * gg);
            float th = 2.f / (1.f + __expf(-2.f * c)) - 1.f;
            float h = go * th;
            float hn = __shfl_down(h, 1, 64);
            if ((m & 1) == 0) {
                ((unsigned int*)hp)[m >> 1] = packh(h, hn);
                *(unsigned int*)(h1relu + ((size_t)t * BATCH + b) * HD1 + m) =
                    packh(fmaxf(h, 0.f), fmaxf(hn, 0.f));
            }
        }
        __syncthreads();                      // hp(t+1) ready
    }
}

// ---------------------------------------------------------------------------
// Phase 2: LSTM layer 2 — 2-way SPLIT-K. 1024 blocks x 1024 threads, one
// batch per block.
//
// R4 RATIONALE (from R0-R3): duration scales exactly with 1/VALUBusy, i.e.
// latency-bound; resident waves are the only lever (R2 64-reg+spill 1319us
// beat R3 92-reg no-spill 1931us). Need VGPR<=64 AND no spill -> cut
// per-thread weights to 45 dwords via split-K:
//   workers 0..799: (half, row). half0 = h1 dwords 0..39 + h2 dwords 0..4
//   (+bias); half1 = h2 dwords 5..49. Both write partials to part[2][400].
//   threads 0..99 combine: z = p0+p1, all 4 gates, c-update, packed h2 write
//   (no gates[] array -> still 2 barriers/step).
// hp layout (96 dwords, 16B aligned): [0..39] h1, [40..44] h2 d0-4,
// [48..92] h2 d5-49 -> each half reads 11x ds_read_b128 + 1x b32, broadcast.
// Waves 13-15 skip dots (wave-uniform branch); wave 13 stages h1 w/ prefetch.
// __launch_bounds__(1024,2): 2 blocks x 16 waves = 32 waves/CU -> 64-reg cap.
// ---------------------------------------------------------------------------
__global__ __launch_bounds__(1024, 2)
void lstm2_kernel(const _Float16* __restrict__ h1relu,
                  const unsigned int* __restrict__ w2t,
                  const float* __restrict__ b_ih2,
                  const float* __restrict__ b_hh2,
                  float* __restrict__ h2last)
{
    const int j  = threadIdx.x;
    const int b0 = blockIdx.x;                 // one batch per block
    const int wv = j >> 6;                     // wave id 0..15
    const bool worker = (j < 2 * NR2);         // threads 0..799
    const int  wr   = worker ? j : (2 * NR2 - 1);
    const int  half = wr / NR2;                // 0 or 1
    const int  row  = wr % NR2;                // gate-row 0..399

    unsigned int w[HALF_DW];
#pragma unroll
    for (int d = 0; d < HALF_DW; d++)
        w[d] = w2t[(half * HALF_DW + d) * NR2 + row];
    const float bias = (half == 0) ? (b_ih2[row] + b_hh2[row]) : 0.f;

    __shared__ __align__(16) unsigned int hp[2 * HP_PAD];  // 96 dwords
    __shared__ float part[2][NR2];

    if (j >= W1_DW && j < 2 * HP_PAD) hp[j] = 0u;   // zero h2 region (40..95)
    float c0 = 0.f;

    // stagers: wave 13, threads 832..871 each own one h1 dword
    const int  sj = j - 832;
    const bool stager = (sj >= 0) && (sj < W1_DW);
    const int  sk = stager ? sj : 0;
    unsigned int pf = 0;
    if (stager)
        pf = *(const unsigned int*)(h1relu + (size_t)b0 * HD1 + 2 * sk);

    const int base = half * HP_PAD;            // dword base in hp

    for (int t = 0; t < T_STEPS; t++) {
        if (stager)
            hp[sk] = pf;                       // stage h1(t)
        __syncthreads();                       // hp: h1(t) + h2(t) ready

        if (wv < 13) {
            // dot phase: all lanes of waves 0..12 (uniform); clamped lanes
            // 800..831 compute garbage and don't write.
            float aP = bias, aQ = 0.f, aR = 0.f, aS = 0.f;
#pragma unroll
            for (int k4 = 0; k4 < 11; k4++) {  // 44 dwords, 16B-aligned
                uint4 U = *(const uint4*)&hp[base + 4 * k4];
                aP = dot2(bch(w[4 * k4 + 0]), bch(U.x), aP);
                aQ = dot2(bch(w[4 * k4 + 1]), bch(U.y), aQ);
                aR = dot2(bch(w[4 * k4 + 2]), bch(U.z), aR);
                aS = dot2(bch(w[4 * k4 + 3]), bch(U.w), aS);
            }
            aP = dot2(bch(w[44]), bch(hp[base + 44]), aP);   // 45th dword
            float z = (aP + aR) + (aQ + aS);
            if (worker) part[half][row] = z;
        } else if (stager && t + 1 < T_STEPS) {
            // wave 13: prefetch next h1 (latency hidden under dot phase)
            pf = *(const unsigned int*)(h1relu +
                     ((size_t)(t + 1) * BATCH + b0) * HD1 + 2 * sk);
        }
        __syncthreads();                       // part ready

        if (j < HD2) {                         // combine: threads 0..99
            float zi = part[0][j]           + part[1][j];
            float zf = part[0][HD2 + j]     + part[1][HD2 + j];
            float zg = part[0][2 * HD2 + j] + part[1][2 * HD2 + j];
            float zo = part[0][3 * HD2 + j] + part[1][3 * HD2 + j];
            float gi = 1.f / (1.f + __expf(-zi));
            float gf = 1.f / (1.f + __expf(-zf));
            float gg = 2.f / (1.f + __expf(-2.f * zg)) - 1.f;   // tanh
            float go = 1.f / (1.f + __expf(-zo));
            c0 = fmaf(gf, c0, gi * gg);
            float th = 2.f / (1.f + __expf(-2.f * c0)) - 1.f;
            float h0 = go * th;
            float h0n = __shfl_down(h0, 1, 64);
            if ((j & 1) == 0) {
                int p = j >> 1;                // h2 dword 0..49
                hp[(p < 5) ? (W1_DW + p) : (HP_PAD - 5 + p)] = packh(h0, h0n);
            }
            if (t == T_STEPS - 1)
                h2last[(size_t)b0 * HD2 + j] = fmaxf(h0, 0.f);
        }
        // loop-top stage + barrier A covers h2(t+1) visibility
    }
}

// ---------------------------------------------------------------------------
// Head: out[b] = W_l2 @ relu(W_l1 @ h2last[b] + b_l1) + b_l2
// ---------------------------------------------------------------------------
__global__ __launch_bounds__(64)
void head_kernel(const float* __restrict__ h2last,
                 const float* __restrict__ W_l1,
                 const float* __restrict__ b_l1,
                 const float* __restrict__ W_l2,
                 const float* __restrict__ b_l2,
                 float* __restrict__ out)
{
    int b = blockIdx.x * 64 + threadIdx.x;
    if (b >= BATCH) return;
    const float* h = h2last + (size_t)b * HD2;
    float o = b_l2[0];
#pragma unroll
    for (int u = 0; u < 10; u++) {
        float s = b_l1[u];
#pragma unroll
        for (int k = 0; k < HD2; k++) s = fmaf(W_l1[u * HD2 + k], h[k], s);
        o = fmaf(W_l2[u], fmaxf(s, 0.f), o);
    }
    out[b] = o;
}

extern "C" void kernel_launch(void* const* d_in, const int* in_sizes, int n_in,
                              void* d_out, int out_size, void* d_ws, size_t ws_size,
                              hipStream_t stream)
{
    const float* x     = (const float*)d_in[0];
    const float* W_ih1 = (const float*)d_in[1];
    const float* W_hh1 = (const float*)d_in[2];
    const float* b_ih1 = (const float*)d_in[3];
    const float* b_hh1 = (const float*)d_in[4];
    const float* W_ih2 = (const float*)d_in[5];
    const float* W_hh2 = (const float*)d_in[6];
    const float* b_ih2 = (const float*)d_in[7];
    const float* b_hh2 = (const float*)d_in[8];
    const float* W_l1  = (const float*)d_in[9];
    const float* b_l1  = (const float*)d_in[10];
    const float* W_l2  = (const float*)d_in[11];
    const float* b_l2  = (const float*)d_in[12];
    float* out = (float*)d_out;

    // ws layout: h1relu f16 [t][b][k] (84 MB) | h2last f32 | w1t | w2t
    char* p = (char*)d_ws;
    _Float16* h1relu = (_Float16*)p;           p += (size_t)T_STEPS * BATCH * HD1 * 2;
    float* h2last    = (float*)p;              p += (size_t)BATCH * HD2 * 4;
    unsigned int* w1t = (unsigned int*)p;      p += (size_t)W1_DW * NR1 * 4;
    unsigned int* w2t = (unsigned int*)p;

    int prep_n = W1_DW * NR1 + W2_DW * NR2;
    hipLaunchKernelGGL(prep_kernel, dim3((prep_n + 255) / 256), dim3(256), 0, stream,
                       W_hh1, W_ih2, W_hh2, w1t, w2t);
    hipLaunchKernelGGL(lstm1_kernel, dim3(BATCH), dim3(NR1), 0, stream,
                       x, W_ih1, w1t, b_ih1, b_hh1, h1relu);
    hipLaunchKernelGGL(lstm2_kernel, dim3(BATCH), dim3(1024), 0, stream,
                       h1relu, w2t, b_ih2, b_hh2, h2last);
    hipLaunchKernelGGL(head_kernel, dim3(BATCH / 64), dim3(64), 0, stream,
                       h2last, W_l1, b_l1, W_l2, b_l2, out);
}